// Round 4
// baseline (1353.250 us; speedup 1.0000x reference)
//
#include <hip/hip_runtime.h>
#include <hip/hip_cooperative_groups.h>

namespace cg = cooperative_groups;

// Problem constants (from reference file)
#define N0_SRC 200000
#define N1_DST 50000
#define N2_DST 12000
#define N3_DST 3000
#define NTOT_DST 65000   // N1+N2+N3 (multiple of 4)
#define DH 256           // D_IN == D_H == 256
#define DOUT 64
#define EMAX_TOT 650000  // E0+E1+E2

#define PREP_BLOCKS 2048  // 8 blocks/CU x 256 CUs -- fully co-resident

typedef __attribute__((ext_vector_type(8))) short short8;
typedef __attribute__((ext_vector_type(4))) float f32x4;

__device__ __forceinline__ ushort f2bf(float f) {
    union { float f; uint32_t u; } v; v.f = f;
    uint32_t r = (v.u + 0x7FFF + ((v.u >> 16) & 1)) >> 16;  // RNE
    return (ushort)r;
}
__device__ __forceinline__ float bf2f(ushort u) {
    union { uint32_t u; float f; } v; v.u = ((uint32_t)u) << 16;
    return v.f;
}

// global -> LDS direct copy, 16B per lane. LDS dest is wave-uniform base +
// lane*16 (m104); caller passes the wave-uniform LDS base pointer.
__device__ __forceinline__ void gload16(const ushort* g, ushort* l) {
    __builtin_amdgcn_global_load_lds(
        (const __attribute__((address_space(1))) unsigned int*)g,
        (__attribute__((address_space(3))) unsigned int*)l,
        16, 0, 0);
}

// ---------------------------------------------------------------------------
// Cooperative prep + CSR mega-kernel. R3 lesson: at 256 blocks this was
// 1 wave/SIMD and latency-bound (221 us, 11% occupancy, 0.8% VALU). Now 2048
// blocks (8/CU co-resident) -> 32 waves/CU of TLP over the atomic chains.
// phase 0: zero cnt, convert x[:N1] to bf16, transpose 6 weights
// phase 1: histogram  | phase 2: 2-level exclusive scan | phase 3: fill eidx
// ---------------------------------------------------------------------------
struct PrepArgs {
    const float* x;
    const float* W[6];
    const int* s0; const int* d0; int E0;
    const int* s1; const int* d1; int E1;
    const int* s2; const int* d2; int E2;
    ushort* Wt; ushort* xb50;
    int* cnt; int* off; int* cursor; int* eidx; int* partial;
};

__global__ __launch_bounds__(256) void prep_csr_kernel(PrepArgs a) {
    cg::grid_group grid = cg::this_grid();
    __shared__ int red[4];
    __shared__ int tsum[256];
    __shared__ int pbase;
    const int GT = PREP_BLOCKS * 256;
    int gt = blockIdx.x * 256 + threadIdx.x;
    int t  = threadIdx.x;

    // --- Phase 0a: zero cnt ---
    for (int i = gt; i < NTOT_DST; i += GT) a.cnt[i] = 0;
    // --- Phase 0b: convert x[:N1] fp32 -> bf16 (float4 strided) ---
    {
        const float4* xv = (const float4*)a.x;
        ushort4* xo = (ushort4*)a.xb50;
        const int nv = N1_DST * DH / 4;
        for (int i = gt; i < nv; i += GT) {
            float4 v = xv[i];
            ushort4 o;
            o.x = f2bf(v.x); o.y = f2bf(v.y); o.z = f2bf(v.z); o.w = f2bf(v.w);
            xo[i] = o;
        }
    }
    // --- Phase 0c: six weight transposes W[K][N] -> Wt[N][K] bf16 ---
    for (int i = gt; i < 294912; i += GT) {
        const float* W; ushort* o; int id; int Ndim;
        if (i < 262144) { int wy = i >> 16; id = i & 65535; W = a.W[wy]; o = a.Wt + (wy << 16); Ndim = 256; }
        else { int j = i - 262144; int wy = j >> 14; id = j & 16383; W = a.W[4 + wy]; o = a.Wt + 262144 + (wy << 14); Ndim = 64; }
        int n = id >> 8, k = id & 255;
        o[id] = f2bf(W[k * Ndim + n]);
    }
    grid.sync();

    // --- Phase 1: histogram ---
    for (int e = gt; e < a.E0; e += GT) atomicAdd(&a.cnt[a.d0[e]], 1);
    for (int e = gt; e < a.E1; e += GT) atomicAdd(&a.cnt[N1_DST + a.d1[e]], 1);
    for (int e = gt; e < a.E2; e += GT) atomicAdd(&a.cnt[N1_DST + N2_DST + a.d2[e]], 1);
    grid.sync();

    // --- Phase 2a: per-block sums over 1024-int chunks (blocks 0..63) ---
    if (blockIdx.x < 64) {
        int i = blockIdx.x * 1024 + t * 4;
        int s = 0;
        if (i + 3 < NTOT_DST) {
            int4 v = *(const int4*)(a.cnt + i);
            s = v.x + v.y + v.z + v.w;
        }
#pragma unroll
        for (int d = 32; d; d >>= 1) s += __shfl_down(s, d, 64);
        if ((t & 63) == 0) red[t >> 6] = s;
        __syncthreads();
        if (t == 0) a.partial[blockIdx.x] = red[0] + red[1] + red[2] + red[3];
    }
    grid.sync();

    // --- Phase 2b: blocks 0..63 re-scan the 64 partials, then their chunk ---
    if (blockIdx.x < 64) {
        if (t < 64) {
            int own = a.partial[t];
            int v = own;
#pragma unroll
            for (int d = 1; d < 64; d <<= 1) {
                int u = __shfl_up(v, d, 64);
                if (t >= d) v += u;
            }
            if (t == (int)blockIdx.x) pbase = v - own;  // exclusive prefix
        }
        int i = blockIdx.x * 1024 + t * 4;
        int4 c = make_int4(0, 0, 0, 0);
        if (i + 3 < NTOT_DST) c = *(const int4*)(a.cnt + i);
        int s = c.x + c.y + c.z + c.w;
        tsum[t] = s;
        __syncthreads();
#pragma unroll
        for (int d = 1; d < 256; d <<= 1) {
            int u = (t >= d) ? tsum[t - d] : 0;
            __syncthreads();
            tsum[t] += u;
            __syncthreads();
        }
        int base = pbase + tsum[t] - s;
        if (i + 3 < NTOT_DST) {
            int4 ov;
            ov.x = base;
            ov.y = ov.x + c.x;
            ov.z = ov.y + c.y;
            ov.w = ov.z + c.z;
            *(int4*)(a.off + i) = ov;
            *(int4*)(a.cursor + i) = ov;
            if (i + 4 == NTOT_DST) a.off[NTOT_DST] = ov.w + c.w;
        }
    }
    grid.sync();

    // --- Phase 3: fill eidx ---
    for (int e = gt; e < a.E0; e += GT) { int p = atomicAdd(&a.cursor[a.d0[e]], 1); a.eidx[p] = a.s0[e]; }
    for (int e = gt; e < a.E1; e += GT) { int p = atomicAdd(&a.cursor[N1_DST + a.d1[e]], 1); a.eidx[p] = a.s1[e]; }
    for (int e = gt; e < a.E2; e += GT) { int p = atomicAdd(&a.cursor[N1_DST + N2_DST + a.d2[e]], 1); a.eidx[p] = a.s2[e]; }
}

// ---------------------------------------------------------------------------
// Gather-mean from FP32 source (layer 0): reads x directly, writes bf16.
// One wave per dst; lane owns 4 feats. 8-wide masked batches (8 outstanding
// 16B loads per round -> 2x MLP vs the previous 4-wide version).
// ---------------------------------------------------------------------------
__global__ void gather_mean_f32_kernel(const float* __restrict__ h,
                                       const int* __restrict__ off,
                                       const int* __restrict__ eidx,
                                       ushort* __restrict__ hn,
                                       int num_dst) {
    int w = blockIdx.x * 4 + (threadIdx.x >> 6);
    int lane = threadIdx.x & 63;
    if (w >= num_dst) return;
    int beg = off[w];
    int end = off[w + 1];
    float a0 = 0.f, a1 = 0.f, a2 = 0.f, a3 = 0.f;
    for (int i = beg; i < end; i += 8) {
        int rem = end - i;  // >= 1
        int j1 = i + (rem > 1 ? 1 : 0);
        int j2 = i + (rem > 2 ? 2 : 0);
        int j3 = i + (rem > 3 ? 3 : 0);
        int j4 = i + (rem > 4 ? 4 : 0);
        int j5 = i + (rem > 5 ? 5 : 0);
        int j6 = i + (rem > 6 ? 6 : 0);
        int j7 = i + (rem > 7 ? 7 : 0);
        float m1 = rem > 1 ? 1.f : 0.f;
        float m2 = rem > 2 ? 1.f : 0.f;
        float m3 = rem > 3 ? 1.f : 0.f;
        float m4 = rem > 4 ? 1.f : 0.f;
        float m5 = rem > 5 ? 1.f : 0.f;
        float m6 = rem > 6 ? 1.f : 0.f;
        float m7 = rem > 7 ? 1.f : 0.f;
        int s0 = eidx[i],  s1 = eidx[j1], s2 = eidx[j2], s3 = eidx[j3];
        int s4 = eidx[j4], s5 = eidx[j5], s6 = eidx[j6], s7 = eidx[j7];
        float4 v0 = ((const float4*)(h + (size_t)s0 * DH))[lane];
        float4 v1 = ((const float4*)(h + (size_t)s1 * DH))[lane];
        float4 v2 = ((const float4*)(h + (size_t)s2 * DH))[lane];
        float4 v3 = ((const float4*)(h + (size_t)s3 * DH))[lane];
        float4 v4 = ((const float4*)(h + (size_t)s4 * DH))[lane];
        float4 v5 = ((const float4*)(h + (size_t)s5 * DH))[lane];
        float4 v6 = ((const float4*)(h + (size_t)s6 * DH))[lane];
        float4 v7 = ((const float4*)(h + (size_t)s7 * DH))[lane];
        a0 += (v0.x + m1 * v1.x + m2 * v2.x + m3 * v3.x) +
              (m4 * v4.x + m5 * v5.x + m6 * v6.x + m7 * v7.x);
        a1 += (v0.y + m1 * v1.y + m2 * v2.y + m3 * v3.y) +
              (m4 * v4.y + m5 * v5.y + m6 * v6.y + m7 * v7.y);
        a2 += (v0.z + m1 * v1.z + m2 * v2.z + m3 * v3.z) +
              (m4 * v4.z + m5 * v5.z + m6 * v6.z + m7 * v7.z);
        a3 += (v0.w + m1 * v1.w + m2 * v2.w + m3 * v3.w) +
              (m4 * v4.w + m5 * v5.w + m6 * v6.w + m7 * v7.w);
    }
    float inv = 1.0f / fmaxf((float)(end - beg), 1.0f);
    ushort4 o;
    o.x = f2bf(a0 * inv); o.y = f2bf(a1 * inv);
    o.z = f2bf(a2 * inv); o.w = f2bf(a3 * inv);
    *(ushort4*)(hn + (size_t)w * DH + lane * 4) = o;
}

// ---------------------------------------------------------------------------
// Gather-mean bf16 in -> bf16 out (layers 1/2), 8-wide masked batches.
// ---------------------------------------------------------------------------
__global__ void gather_mean_bf16_kernel(const ushort* __restrict__ h,
                                        const int* __restrict__ off,
                                        const int* __restrict__ eidx,
                                        ushort* __restrict__ hn,
                                        int num_dst) {
    int w = blockIdx.x * 4 + (threadIdx.x >> 6);
    int lane = threadIdx.x & 63;
    if (w >= num_dst) return;
    int beg = off[w];
    int end = off[w + 1];
    float a0 = 0.f, a1 = 0.f, a2 = 0.f, a3 = 0.f;
    for (int i = beg; i < end; i += 8) {
        int rem = end - i;  // >= 1
        int j1 = i + (rem > 1 ? 1 : 0);
        int j2 = i + (rem > 2 ? 2 : 0);
        int j3 = i + (rem > 3 ? 3 : 0);
        int j4 = i + (rem > 4 ? 4 : 0);
        int j5 = i + (rem > 5 ? 5 : 0);
        int j6 = i + (rem > 6 ? 6 : 0);
        int j7 = i + (rem > 7 ? 7 : 0);
        float m1 = rem > 1 ? 1.f : 0.f;
        float m2 = rem > 2 ? 1.f : 0.f;
        float m3 = rem > 3 ? 1.f : 0.f;
        float m4 = rem > 4 ? 1.f : 0.f;
        float m5 = rem > 5 ? 1.f : 0.f;
        float m6 = rem > 6 ? 1.f : 0.f;
        float m7 = rem > 7 ? 1.f : 0.f;
        int s0 = eidx[i],  s1 = eidx[j1], s2 = eidx[j2], s3 = eidx[j3];
        int s4 = eidx[j4], s5 = eidx[j5], s6 = eidx[j6], s7 = eidx[j7];
        ushort4 v0 = ((const ushort4*)(h + (size_t)s0 * DH))[lane];
        ushort4 v1 = ((const ushort4*)(h + (size_t)s1 * DH))[lane];
        ushort4 v2 = ((const ushort4*)(h + (size_t)s2 * DH))[lane];
        ushort4 v3 = ((const ushort4*)(h + (size_t)s3 * DH))[lane];
        ushort4 v4 = ((const ushort4*)(h + (size_t)s4 * DH))[lane];
        ushort4 v5 = ((const ushort4*)(h + (size_t)s5 * DH))[lane];
        ushort4 v6 = ((const ushort4*)(h + (size_t)s6 * DH))[lane];
        ushort4 v7 = ((const ushort4*)(h + (size_t)s7 * DH))[lane];
        a0 += (bf2f(v0.x) + m1 * bf2f(v1.x) + m2 * bf2f(v2.x) + m3 * bf2f(v3.x)) +
              (m4 * bf2f(v4.x) + m5 * bf2f(v5.x) + m6 * bf2f(v6.x) + m7 * bf2f(v7.x));
        a1 += (bf2f(v0.y) + m1 * bf2f(v1.y) + m2 * bf2f(v2.y) + m3 * bf2f(v3.y)) +
              (m4 * bf2f(v4.y) + m5 * bf2f(v5.y) + m6 * bf2f(v6.y) + m7 * bf2f(v7.y));
        a2 += (bf2f(v0.z) + m1 * bf2f(v1.z) + m2 * bf2f(v2.z) + m3 * bf2f(v3.z)) +
              (m4 * bf2f(v4.z) + m5 * bf2f(v5.z) + m6 * bf2f(v6.z) + m7 * bf2f(v7.z));
        a3 += (bf2f(v0.w) + m1 * bf2f(v1.w) + m2 * bf2f(v2.w) + m3 * bf2f(v3.w)) +
              (m4 * bf2f(v4.w) + m5 * bf2f(v5.w) + m6 * bf2f(v6.w) + m7 * bf2f(v7.w));
    }
    float inv = 1.0f / fmaxf((float)(end - beg), 1.0f);
    ushort4 o;
    o.x = f2bf(a0 * inv); o.y = f2bf(a1 * inv);
    o.z = f2bf(a2 * inv); o.w = f2bf(a3 * inv);
    *(ushort4*)(hn + (size_t)w * DH + lane * 4) = o;
}

// ---------------------------------------------------------------------------
// Merged-dual MFMA GEMM: C[M,N] = Ad@Ws + An@Wn + bias (K=256), both passes
// in ONE k-loop. Staging via global_load_lds width-16 into LINEAR LDS tiles
// [rows][32] (64B rows). Bank conflicts handled by the both-sides XOR swizzle
// (rule 21). BM = MT*64, BN = NT*16. M-tail: staged row clamped to M-1.
// ---------------------------------------------------------------------------
template <int MT, int NT, bool RELU, bool OUT_BF16>
__global__ __launch_bounds__(256) void gemm_dual(const ushort* __restrict__ Ad,
                                                 const ushort* __restrict__ An,
                                                 const ushort* __restrict__ Wst,
                                                 const ushort* __restrict__ Wnt,
                                                 const float* __restrict__ bias,
                                                 void* __restrict__ Cv,
                                                 int M, int N) {
    const int K = 256;
    const int BM = MT * 64;
    const int BN = NT * 16;
    __shared__ __align__(16) ushort lds[(2 * BM + 2 * BN) * 32];
    ushort* Asd = lds;
    ushort* Asn = lds + BM * 32;
    ushort* Bss = lds + 2 * BM * 32;
    ushort* Bsn = lds + 2 * BM * 32 + BN * 32;

    int tid  = threadIdx.x;
    int lane = tid & 63;
    int wid  = tid >> 6;
    int q    = lane >> 4;
    int mr   = lane & 15;
    int row0 = blockIdx.y * BM;
    int col0 = blockIdx.x * BN;

    f32x4 acc[MT][NT];
#pragma unroll
    for (int i = 0; i < MT; ++i)
#pragma unroll
        for (int j = 0; j < NT; ++j) acc[i][j] = (f32x4){0.f, 0.f, 0.f, 0.f};

    for (int k0 = 0; k0 < K; k0 += 32) {
        // Stage A tiles (BM x 32, clamped rows), both matrices.
#pragma unroll
        for (int c = 0; c < MT; ++c) {
            int chunk = c * 256 + tid;               // 16B chunk index in tile
            int r   = chunk >> 2;                    // tile row
            int sg  = (chunk & 3) ^ ((r >> 1) & 3);  // swizzled global segment
            int row = row0 + r;
            if (row > M - 1) row = M - 1;
            const ushort* gd = Ad + (size_t)row * K + k0 + sg * 8;
            const ushort* gn = An + (size_t)row * K + k0 + sg * 8;
            int cb = (c * 256 + (tid & ~63)) * 8;    // wave-uniform LDS base
            gload16(gd, Asd + cb);
            gload16(gn, Asn + cb);
        }
        // Stage B tiles (BN x 32), both weight matrices. Rows always valid.
#pragma unroll
        for (int c = 0; c < NT / 4; ++c) {
            int chunk = c * 256 + tid;
            int r  = chunk >> 2;
            int sg = (chunk & 3) ^ ((r >> 1) & 3);
            const ushort* gs = Wst + (size_t)(col0 + r) * K + k0 + sg * 8;
            const ushort* gw = Wnt + (size_t)(col0 + r) * K + k0 + sg * 8;
            int cb = (c * 256 + (tid & ~63)) * 8;
            gload16(gs, Bss + cb);
            gload16(gw, Bsn + cb);
        }
        __syncthreads();  // compiler drains vmcnt(0) before s_barrier

        short8 ad[MT], an[MT];
#pragma unroll
        for (int mt = 0; mt < MT; ++mt) {
            int rho = wid * (MT * 16) + mt * 16 + mr;
            int o   = rho * 32 + ((q ^ ((rho >> 1) & 3)) * 8);
            ad[mt] = *(const short8*)(Asd + o);
            an[mt] = *(const short8*)(Asn + o);
        }
#pragma unroll
        for (int nt = 0; nt < NT; ++nt) {
            int rho = nt * 16 + mr;
            int o   = rho * 32 + ((q ^ ((rho >> 1) & 3)) * 8);
            short8 bs = *(const short8*)(Bss + o);
            short8 bn = *(const short8*)(Bsn + o);
#pragma unroll
            for (int mt = 0; mt < MT; ++mt)
                acc[mt][nt] = __builtin_amdgcn_mfma_f32_16x16x32_bf16(
                    ad[mt], bs, acc[mt][nt], 0, 0, 0);
#pragma unroll
            for (int mt = 0; mt < MT; ++mt)
                acc[mt][nt] = __builtin_amdgcn_mfma_f32_16x16x32_bf16(
                    an[mt], bn, acc[mt][nt], 0, 0, 0);
        }
        __syncthreads();
    }

    // Epilogue: C/D layout col = lane&15, row = quad*4 + reg
#pragma unroll
    for (int mt = 0; mt < MT; ++mt) {
#pragma unroll
        for (int i = 0; i < 4; ++i) {
            int row = row0 + wid * (MT * 16) + mt * 16 + q * 4 + i;
            if (row >= M) continue;
#pragma unroll
            for (int nt = 0; nt < NT; ++nt) {
                int col = col0 + nt * 16 + mr;
                float v = acc[mt][nt][i] + bias[col];
                if (RELU) v = fmaxf(v, 0.0f);
                if (OUT_BF16) ((ushort*)Cv)[(size_t)row * N + col] = f2bf(v);
                else          ((float*)Cv)[(size_t)row * N + col] = v;
            }
        }
    }
}

extern "C" void kernel_launch(void* const* d_in, const int* in_sizes, int n_in,
                              void* d_out, int out_size, void* d_ws, size_t ws_size,
                              hipStream_t stream) {
    const float* x    = (const float*)d_in[0];
    const int* src0   = (const int*)d_in[1];
    const int* dst0   = (const int*)d_in[2];
    const int* src1   = (const int*)d_in[3];
    const int* dst1   = (const int*)d_in[4];
    const int* src2   = (const int*)d_in[5];
    const int* dst2   = (const int*)d_in[6];
    const float* Ws0  = (const float*)d_in[10];
    const float* Wn0  = (const float*)d_in[11];
    const float* b0   = (const float*)d_in[12];
    const float* Ws1  = (const float*)d_in[13];
    const float* Wn1  = (const float*)d_in[14];
    const float* b1   = (const float*)d_in[15];
    const float* Ws2  = (const float*)d_in[16];
    const float* Wn2  = (const float*)d_in[17];
    const float* b2   = (const float*)d_in[18];
    float* out = (float*)d_out;

    int E0 = in_sizes[1];
    int E1 = in_sizes[3];
    int E2 = in_sizes[5];

    // Workspace layout (shorts first, then ints; all 16B aligned)
    ushort* wsu  = (ushort*)d_ws;
    ushort* xb50 = wsu;                               // N1*256 (x[:N1] bf16)
    ushort* hn0b = xb50 + (size_t)N1_DST * DH;        // N1*256
    ushort* h1b  = hn0b + (size_t)N1_DST * DH;        // N1*256
    ushort* hn1b = h1b  + (size_t)N1_DST * DH;        // N2*256
    ushort* h2b  = hn1b + (size_t)N2_DST * DH;        // N2*256
    ushort* hn2b = h2b  + (size_t)N2_DST * DH;        // N3*256
    ushort* Wt   = hn2b + (size_t)N3_DST * DH;        // 294912 shorts (6 weights)
    ushort* Ws0t = Wt;
    ushort* Wn0t = Wt + 65536;
    ushort* Ws1t = Wt + 131072;
    ushort* Wn1t = Wt + 196608;
    ushort* Ws2t = Wt + 262144;
    ushort* Wn2t = Wt + 278528;
    int* cnt     = (int*)(Wt + 294912);               // NTOT_DST
    int* off     = cnt + NTOT_DST;                    // NTOT_DST+1 (+pad)
    int* cursor  = off + NTOT_DST + 4;                // NTOT_DST
    int* eidx    = cursor + NTOT_DST;                 // EMAX_TOT
    int* partial = eidx + EMAX_TOT;                   // 64 block partials

    // --- Dispatch 1: cooperative prep + CSR build (2048 co-resident blocks) ---
    PrepArgs pa;
    pa.x = x;
    pa.W[0] = Ws0; pa.W[1] = Wn0; pa.W[2] = Ws1;
    pa.W[3] = Wn1; pa.W[4] = Ws2; pa.W[5] = Wn2;
    pa.s0 = src0; pa.d0 = dst0; pa.E0 = E0;
    pa.s1 = src1; pa.d1 = dst1; pa.E1 = E1;
    pa.s2 = src2; pa.d2 = dst2; pa.E2 = E2;
    pa.Wt = Wt; pa.xb50 = xb50;
    pa.cnt = cnt; pa.off = off; pa.cursor = cursor;
    pa.eidx = eidx; pa.partial = partial;
    void* kargs[] = { &pa };
    hipLaunchCooperativeKernel((void*)prep_csr_kernel, dim3(PREP_BLOCKS), dim3(256),
                               kargs, 0, stream);

    const int* off0 = off;
    const int* off1 = off + N1_DST;
    const int* off2 = off + N1_DST + N2_DST;

    // ---- Layer 0: x -> h1 (gather reads fp32 x directly) ----
    gather_mean_f32_kernel<<<(N1_DST + 3) / 4, 256, 0, stream>>>(x, off0, eidx, hn0b, N1_DST);
    gemm_dual<2, 8, false, true><<<dim3(DH / 128, (N1_DST + 127) / 128), 256, 0, stream>>>(
        xb50, hn0b, Ws0t, Wn0t, b0, h1b, N1_DST, DH);

    // ---- Layer 1: h1 -> h2 (ReLU on output) ----
    gather_mean_bf16_kernel<<<(N2_DST + 3) / 4, 256, 0, stream>>>(h1b, off1, eidx, hn1b, N2_DST);
    gemm_dual<2, 8, true, true><<<dim3(DH / 128, (N2_DST + 127) / 128), 256, 0, stream>>>(
        h1b, hn1b, Ws1t, Wn1t, b1, h2b, N2_DST, DH);

    // ---- Layer 2: h2 -> out (fp32 output, BM=64) ----
    gather_mean_bf16_kernel<<<(N3_DST + 3) / 4, 256, 0, stream>>>(h2b, off2, eidx, hn2b, N3_DST);
    gemm_dual<1, 4, false, false><<<dim3(DOUT / 64, (N3_DST + 63) / 64), 256, 0, stream>>>(
        h2b, hn2b, Ws2t, Wn2t, b2, out, N3_DST, DOUT);
}

// Round 5
// 509.032 us; speedup vs baseline: 2.6585x; 2.6585x over previous
//
#include <hip/hip_runtime.h>

// Problem constants (from reference file)
#define N0_SRC 200000
#define N1_DST 50000
#define N2_DST 12000
#define N3_DST 3000
#define NTOT_DST 65000   // N1+N2+N3 (multiple of 4)
#define DH 256           // D_IN == D_H == 256
#define DOUT 64
#define EMAX_TOT 650000  // E0+E1+E2

#define HIST_BLOCKS 1024   // latency-bound region of conv_trans_hist
#define CONV_BLOCKS 3072   // BW-bound region (convert + transposes)

typedef __attribute__((ext_vector_type(8))) short short8;
typedef __attribute__((ext_vector_type(4))) float f32x4;

__device__ __forceinline__ ushort f2bf(float f) {
    union { float f; uint32_t u; } v; v.f = f;
    uint32_t r = (v.u + 0x7FFF + ((v.u >> 16) & 1)) >> 16;  // RNE
    return (ushort)r;
}
__device__ __forceinline__ float bf2f(ushort u) {
    union { uint32_t u; float f; } v; v.u = ((uint32_t)u) << 16;
    return v.f;
}

// global -> LDS direct copy, 16B per lane. LDS dest is wave-uniform base +
// lane*16 (m104); caller passes the wave-uniform LDS base pointer.
__device__ __forceinline__ void gload16(const ushort* g, ushort* l) {
    __builtin_amdgcn_global_load_lds(
        (const __attribute__((address_space(1))) unsigned int*)g,
        (__attribute__((address_space(3))) unsigned int*)l,
        16, 0, 0);
}

// ---------------------------------------------------------------------------
// Fused convert + transpose + histogram. The histogram (atomic latency-bound)
// and the x fp32->bf16 convert (HBM BW-bound) are INDEPENDENT until gather0 /
// scan respectively -- run them concurrently in one dispatch, partitioned by
// blockIdx. Hist blocks first (dispatched earliest -> overlap from t=0).
// R4 lesson: no grid.sync anywhere (cooperative barrier cost >> work).
// ---------------------------------------------------------------------------
__global__ __launch_bounds__(256) void conv_trans_hist(
    const float* __restrict__ x, ushort* __restrict__ xb,
    const float* __restrict__ W0, const float* __restrict__ W1,
    const float* __restrict__ W2, const float* __restrict__ W3,
    const float* __restrict__ W4, const float* __restrict__ W5,
    ushort* __restrict__ Wt,
    const int* __restrict__ d0, int E0,
    const int* __restrict__ d1, int E1,
    const int* __restrict__ d2, int E2,
    int* __restrict__ cnt) {
    int bid = blockIdx.x, t = threadIdx.x;
    if (bid < HIST_BLOCKS) {
        const int S = HIST_BLOCKS * 256;
        int g = bid * 256 + t;
        for (int e = g; e < E0; e += S) atomicAdd(&cnt[d0[e]], 1);
        for (int e = g; e < E1; e += S) atomicAdd(&cnt[N1_DST + d1[e]], 1);
        for (int e = g; e < E2; e += S) atomicAdd(&cnt[N1_DST + N2_DST + d2[e]], 1);
        return;
    }
    const int S = CONV_BLOCKS * 256;
    int g = (bid - HIST_BLOCKS) * 256 + t;
    // Convert ALL of x fp32 -> bf16 (float4 grid-stride; exact multiple).
    {
        const float4* xv = (const float4*)x;
        ushort4* xo = (ushort4*)xb;
        const int nv = N0_SRC * (DH / 4);  // 12.8M float4 chunks
        for (int i = g; i < nv; i += S) {
            float4 v = xv[i];
            ushort4 o;
            o.x = f2bf(v.x); o.y = f2bf(v.y); o.z = f2bf(v.z); o.w = f2bf(v.w);
            xo[i] = o;
        }
    }
    // Six weight transposes W[K][N] -> Wt[N][K] bf16 (flat mapping).
    for (int i = g; i < 294912; i += S) {
        const float* W; ushort* o; int id; int Ndim;
        if (i < 262144) { int wy = i >> 16; id = i & 65535;
            const float* ws[4] = {W0, W1, W2, W3};
            W = ws[wy]; o = Wt + (wy << 16); Ndim = 256; }
        else { int j = i - 262144; int wy = j >> 14; id = j & 16383;
            W = wy ? W5 : W4; o = Wt + 262144 + (wy << 14); Ndim = 64; }
        int n = id >> 8, k = id & 255;
        o[id] = f2bf(W[k * Ndim + n]);
    }
}

// ---------------------------------------------------------------------------
// fill3: scatter edges into CSR slots (cursor atomics).
// ---------------------------------------------------------------------------
__global__ void fill3_kernel(const int* __restrict__ s0, const int* __restrict__ d0, int E0,
                             const int* __restrict__ s1, const int* __restrict__ d1, int E1,
                             const int* __restrict__ s2, const int* __restrict__ d2, int E2,
                             int* __restrict__ cursor, int* __restrict__ eidx) {
    int layer = blockIdx.y;
    const int* src; const int* dst; int E; int base;
    if (layer == 0)      { src = s0; dst = d0; E = E0; base = 0; }
    else if (layer == 1) { src = s1; dst = d1; E = E1; base = N1_DST; }
    else                 { src = s2; dst = d2; E = E2; base = N1_DST + N2_DST; }
    int e = blockIdx.x * 256 + threadIdx.x;
    if (e < E) {
        int p = atomicAdd(&cursor[base + dst[e]], 1);
        eidx[p] = src[e];
    }
}

// ---------------------------------------------------------------------------
// 2-phase coalesced exclusive scan (n multiple of 4; 64 blocks).
// ---------------------------------------------------------------------------
__global__ void scan_phase_a(const int* __restrict__ cnt, int* __restrict__ partial, int n) {
    __shared__ int red[4];
    int t = threadIdx.x;
    int i = blockIdx.x * 1024 + t * 4;
    int s = 0;
    if (i + 3 < n) {
        int4 v = *(const int4*)(cnt + i);
        s = v.x + v.y + v.z + v.w;
    }
#pragma unroll
    for (int d = 32; d; d >>= 1) s += __shfl_down(s, d, 64);
    if ((t & 63) == 0) red[t >> 6] = s;
    __syncthreads();
    if (t == 0) partial[blockIdx.x] = red[0] + red[1] + red[2] + red[3];
}

__global__ void scan_phase_c(const int* __restrict__ cnt, const int* __restrict__ partial,
                             int* __restrict__ off, int* __restrict__ cursor, int n) {
    __shared__ int tsum[256];
    __shared__ int pbase;
    int t = threadIdx.x;
    if (t < 64) {
        int own = partial[t];
        int v = own;
#pragma unroll
        for (int d = 1; d < 64; d <<= 1) {
            int u = __shfl_up(v, d, 64);
            if (t >= d) v += u;
        }
        if (t == (int)blockIdx.x) pbase = v - own;  // exclusive prefix
    }
    int i = blockIdx.x * 1024 + t * 4;
    int4 c = make_int4(0, 0, 0, 0);
    if (i + 3 < n) c = *(const int4*)(cnt + i);
    int s = c.x + c.y + c.z + c.w;
    tsum[t] = s;
    __syncthreads();
#pragma unroll
    for (int d = 1; d < 256; d <<= 1) {
        int u = (t >= d) ? tsum[t - d] : 0;
        __syncthreads();
        tsum[t] += u;
        __syncthreads();
    }
    int base = pbase + tsum[t] - s;
    if (i + 3 < n) {
        int4 ov;
        ov.x = base;
        ov.y = ov.x + c.x;
        ov.z = ov.y + c.y;
        ov.w = ov.z + c.z;
        *(int4*)(off + i) = ov;
        *(int4*)(cursor + i) = ov;
        if (i + 4 == n) off[n] = ov.w + c.w;
    }
}

// ---------------------------------------------------------------------------
// Gather-mean bf16 in -> bf16 out. One wave per dst; lane owns 4 feats.
// 8-wide masked batches: 8 outstanding 16B/8B loads per round for MLP.
// ---------------------------------------------------------------------------
__global__ void gather_mean_bf16_kernel(const ushort* __restrict__ h,
                                        const int* __restrict__ off,
                                        const int* __restrict__ eidx,
                                        ushort* __restrict__ hn,
                                        int num_dst) {
    int w = blockIdx.x * 4 + (threadIdx.x >> 6);
    int lane = threadIdx.x & 63;
    if (w >= num_dst) return;
    int beg = off[w];
    int end = off[w + 1];
    float a0 = 0.f, a1 = 0.f, a2 = 0.f, a3 = 0.f;
    for (int i = beg; i < end; i += 8) {
        int rem = end - i;  // >= 1
        int j1 = i + (rem > 1 ? 1 : 0);
        int j2 = i + (rem > 2 ? 2 : 0);
        int j3 = i + (rem > 3 ? 3 : 0);
        int j4 = i + (rem > 4 ? 4 : 0);
        int j5 = i + (rem > 5 ? 5 : 0);
        int j6 = i + (rem > 6 ? 6 : 0);
        int j7 = i + (rem > 7 ? 7 : 0);
        float m1 = rem > 1 ? 1.f : 0.f;
        float m2 = rem > 2 ? 1.f : 0.f;
        float m3 = rem > 3 ? 1.f : 0.f;
        float m4 = rem > 4 ? 1.f : 0.f;
        float m5 = rem > 5 ? 1.f : 0.f;
        float m6 = rem > 6 ? 1.f : 0.f;
        float m7 = rem > 7 ? 1.f : 0.f;
        int s0 = eidx[i],  s1 = eidx[j1], s2 = eidx[j2], s3 = eidx[j3];
        int s4 = eidx[j4], s5 = eidx[j5], s6 = eidx[j6], s7 = eidx[j7];
        ushort4 v0 = ((const ushort4*)(h + (size_t)s0 * DH))[lane];
        ushort4 v1 = ((const ushort4*)(h + (size_t)s1 * DH))[lane];
        ushort4 v2 = ((const ushort4*)(h + (size_t)s2 * DH))[lane];
        ushort4 v3 = ((const ushort4*)(h + (size_t)s3 * DH))[lane];
        ushort4 v4 = ((const ushort4*)(h + (size_t)s4 * DH))[lane];
        ushort4 v5 = ((const ushort4*)(h + (size_t)s5 * DH))[lane];
        ushort4 v6 = ((const ushort4*)(h + (size_t)s6 * DH))[lane];
        ushort4 v7 = ((const ushort4*)(h + (size_t)s7 * DH))[lane];
        a0 += (bf2f(v0.x) + m1 * bf2f(v1.x) + m2 * bf2f(v2.x) + m3 * bf2f(v3.x)) +
              (m4 * bf2f(v4.x) + m5 * bf2f(v5.x) + m6 * bf2f(v6.x) + m7 * bf2f(v7.x));
        a1 += (bf2f(v0.y) + m1 * bf2f(v1.y) + m2 * bf2f(v2.y) + m3 * bf2f(v3.y)) +
              (m4 * bf2f(v4.y) + m5 * bf2f(v5.y) + m6 * bf2f(v6.y) + m7 * bf2f(v7.y));
        a2 += (bf2f(v0.z) + m1 * bf2f(v1.z) + m2 * bf2f(v2.z) + m3 * bf2f(v3.z)) +
              (m4 * bf2f(v4.z) + m5 * bf2f(v5.z) + m6 * bf2f(v6.z) + m7 * bf2f(v7.z));
        a3 += (bf2f(v0.w) + m1 * bf2f(v1.w) + m2 * bf2f(v2.w) + m3 * bf2f(v3.w)) +
              (m4 * bf2f(v4.w) + m5 * bf2f(v5.w) + m6 * bf2f(v6.w) + m7 * bf2f(v7.w));
    }
    float inv = 1.0f / fmaxf((float)(end - beg), 1.0f);
    ushort4 o;
    o.x = f2bf(a0 * inv); o.y = f2bf(a1 * inv);
    o.z = f2bf(a2 * inv); o.w = f2bf(a3 * inv);
    *(ushort4*)(hn + (size_t)w * DH + lane * 4) = o;
}

// ---------------------------------------------------------------------------
// Merged-dual MFMA GEMM: C[M,N] = Ad@Ws + An@Wn + bias (K=256), both passes
// in ONE k-loop. Staging via global_load_lds width-16 into LINEAR LDS tiles
// [rows][32] (64B rows). Bank conflicts handled by the both-sides XOR swizzle
// (rule 21). BM = MT*64, BN = NT*16. M-tail: staged row clamped to M-1.
// ---------------------------------------------------------------------------
template <int MT, int NT, bool RELU, bool OUT_BF16>
__global__ __launch_bounds__(256) void gemm_dual(const ushort* __restrict__ Ad,
                                                 const ushort* __restrict__ An,
                                                 const ushort* __restrict__ Wst,
                                                 const ushort* __restrict__ Wnt,
                                                 const float* __restrict__ bias,
                                                 void* __restrict__ Cv,
                                                 int M, int N) {
    const int K = 256;
    const int BM = MT * 64;
    const int BN = NT * 16;
    __shared__ __align__(16) ushort lds[(2 * BM + 2 * BN) * 32];
    ushort* Asd = lds;
    ushort* Asn = lds + BM * 32;
    ushort* Bss = lds + 2 * BM * 32;
    ushort* Bsn = lds + 2 * BM * 32 + BN * 32;

    int tid  = threadIdx.x;
    int lane = tid & 63;
    int wid  = tid >> 6;
    int q    = lane >> 4;
    int mr   = lane & 15;
    int row0 = blockIdx.y * BM;
    int col0 = blockIdx.x * BN;

    f32x4 acc[MT][NT];
#pragma unroll
    for (int i = 0; i < MT; ++i)
#pragma unroll
        for (int j = 0; j < NT; ++j) acc[i][j] = (f32x4){0.f, 0.f, 0.f, 0.f};

    for (int k0 = 0; k0 < K; k0 += 32) {
        // Stage A tiles (BM x 32, clamped rows), both matrices.
#pragma unroll
        for (int c = 0; c < MT; ++c) {
            int chunk = c * 256 + tid;               // 16B chunk index in tile
            int r   = chunk >> 2;                    // tile row
            int sg  = (chunk & 3) ^ ((r >> 1) & 3);  // swizzled global segment
            int row = row0 + r;
            if (row > M - 1) row = M - 1;
            const ushort* gd = Ad + (size_t)row * K + k0 + sg * 8;
            const ushort* gn = An + (size_t)row * K + k0 + sg * 8;
            int cb = (c * 256 + (tid & ~63)) * 8;    // wave-uniform LDS base
            gload16(gd, Asd + cb);
            gload16(gn, Asn + cb);
        }
        // Stage B tiles (BN x 32), both weight matrices. Rows always valid.
#pragma unroll
        for (int c = 0; c < NT / 4; ++c) {
            int chunk = c * 256 + tid;
            int r  = chunk >> 2;
            int sg = (chunk & 3) ^ ((r >> 1) & 3);
            const ushort* gs = Wst + (size_t)(col0 + r) * K + k0 + sg * 8;
            const ushort* gw = Wnt + (size_t)(col0 + r) * K + k0 + sg * 8;
            int cb = (c * 256 + (tid & ~63)) * 8;
            gload16(gs, Bss + cb);
            gload16(gw, Bsn + cb);
        }
        __syncthreads();  // compiler drains vmcnt(0) before s_barrier

        short8 ad[MT], an[MT];
#pragma unroll
        for (int mt = 0; mt < MT; ++mt) {
            int rho = wid * (MT * 16) + mt * 16 + mr;
            int o   = rho * 32 + ((q ^ ((rho >> 1) & 3)) * 8);
            ad[mt] = *(const short8*)(Asd + o);
            an[mt] = *(const short8*)(Asn + o);
        }
#pragma unroll
        for (int nt = 0; nt < NT; ++nt) {
            int rho = nt * 16 + mr;
            int o   = rho * 32 + ((q ^ ((rho >> 1) & 3)) * 8);
            short8 bs = *(const short8*)(Bss + o);
            short8 bn = *(const short8*)(Bsn + o);
#pragma unroll
            for (int mt = 0; mt < MT; ++mt)
                acc[mt][nt] = __builtin_amdgcn_mfma_f32_16x16x32_bf16(
                    ad[mt], bs, acc[mt][nt], 0, 0, 0);
#pragma unroll
            for (int mt = 0; mt < MT; ++mt)
                acc[mt][nt] = __builtin_amdgcn_mfma_f32_16x16x32_bf16(
                    an[mt], bn, acc[mt][nt], 0, 0, 0);
        }
        __syncthreads();
    }

    // Epilogue: C/D layout col = lane&15, row = quad*4 + reg
#pragma unroll
    for (int mt = 0; mt < MT; ++mt) {
#pragma unroll
        for (int i = 0; i < 4; ++i) {
            int row = row0 + wid * (MT * 16) + mt * 16 + q * 4 + i;
            if (row >= M) continue;
#pragma unroll
            for (int nt = 0; nt < NT; ++nt) {
                int col = col0 + nt * 16 + mr;
                float v = acc[mt][nt][i] + bias[col];
                if (RELU) v = fmaxf(v, 0.0f);
                if (OUT_BF16) ((ushort*)Cv)[(size_t)row * N + col] = f2bf(v);
                else          ((float*)Cv)[(size_t)row * N + col] = v;
            }
        }
    }
}

extern "C" void kernel_launch(void* const* d_in, const int* in_sizes, int n_in,
                              void* d_out, int out_size, void* d_ws, size_t ws_size,
                              hipStream_t stream) {
    const float* x    = (const float*)d_in[0];
    const int* src0   = (const int*)d_in[1];
    const int* dst0   = (const int*)d_in[2];
    const int* src1   = (const int*)d_in[3];
    const int* dst1   = (const int*)d_in[4];
    const int* src2   = (const int*)d_in[5];
    const int* dst2   = (const int*)d_in[6];
    const float* Ws0  = (const float*)d_in[10];
    const float* Wn0  = (const float*)d_in[11];
    const float* b0   = (const float*)d_in[12];
    const float* Ws1  = (const float*)d_in[13];
    const float* Wn1  = (const float*)d_in[14];
    const float* b1   = (const float*)d_in[15];
    const float* Ws2  = (const float*)d_in[16];
    const float* Wn2  = (const float*)d_in[17];
    const float* b2   = (const float*)d_in[18];
    float* out = (float*)d_out;

    int E0 = in_sizes[1];
    int E1 = in_sizes[3];
    int E2 = in_sizes[5];

    // Workspace layout (shorts first, then ints; all 16B aligned)
    ushort* wsu  = (ushort*)d_ws;
    ushort* xb   = wsu;                               // N0*256 (all of x, bf16)
    ushort* hn0b = xb   + (size_t)N0_SRC * DH;        // N1*256
    ushort* h1b  = hn0b + (size_t)N1_DST * DH;        // N1*256
    ushort* hn1b = h1b  + (size_t)N1_DST * DH;        // N2*256
    ushort* h2b  = hn1b + (size_t)N2_DST * DH;        // N2*256
    ushort* hn2b = h2b  + (size_t)N2_DST * DH;        // N3*256
    ushort* Wt   = hn2b + (size_t)N3_DST * DH;        // 294912 shorts (6 weights)
    ushort* Ws0t = Wt;
    ushort* Wn0t = Wt + 65536;
    ushort* Ws1t = Wt + 131072;
    ushort* Wn1t = Wt + 196608;
    ushort* Ws2t = Wt + 262144;
    ushort* Wn2t = Wt + 278528;
    int* cnt     = (int*)(Wt + 294912);               // NTOT_DST
    int* off     = cnt + NTOT_DST;                    // NTOT_DST+1 (+pad)
    int* cursor  = off + NTOT_DST + 4;                // NTOT_DST
    int* eidx    = cursor + NTOT_DST;                 // EMAX_TOT
    int* partial = eidx + EMAX_TOT;                   // 64 block partials

    int Emax = max(max(E0, E1), E2);
    int nb = (NTOT_DST + 1023) / 1024;  // = 64

    // 1) zero cnt (capture-safe, proven in R0)
    hipMemsetAsync(cnt, 0, NTOT_DST * sizeof(int), stream);
    // 2) fused convert(all x) + weight transposes + histogram (overlapped)
    conv_trans_hist<<<HIST_BLOCKS + CONV_BLOCKS, 256, 0, stream>>>(
        x, xb, Ws0, Wn0, Ws1, Wn1, Ws2, Wn2, Wt,
        dst0, E0, dst1, E1, dst2, E2, cnt);
    // 3-4) scan
    scan_phase_a<<<nb, 256, 0, stream>>>(cnt, partial, NTOT_DST);
    scan_phase_c<<<nb, 256, 0, stream>>>(cnt, partial, off, cursor, NTOT_DST);
    // 5) fill CSR
    fill3_kernel<<<dim3((Emax + 255) / 256, 3), 256, 0, stream>>>(
        src0, dst0, E0, src1, dst1, E1, src2, dst2, E2, cursor, eidx);

    const int* off0 = off;
    const int* off1 = off + N1_DST;
    const int* off2 = off + N1_DST + N2_DST;

    // ---- Layer 0: x -> h1 (gather reads warm bf16 xb) ----
    gather_mean_bf16_kernel<<<(N1_DST + 3) / 4, 256, 0, stream>>>(xb, off0, eidx, hn0b, N1_DST);
    gemm_dual<2, 8, false, true><<<dim3(DH / 128, (N1_DST + 127) / 128), 256, 0, stream>>>(
        xb, hn0b, Ws0t, Wn0t, b0, h1b, N1_DST, DH);

    // ---- Layer 1: h1 -> h2 (ReLU on output) ----
    gather_mean_bf16_kernel<<<(N2_DST + 3) / 4, 256, 0, stream>>>(h1b, off1, eidx, hn1b, N2_DST);
    gemm_dual<2, 8, true, true><<<dim3(DH / 128, (N2_DST + 127) / 128), 256, 0, stream>>>(
        h1b, hn1b, Ws1t, Wn1t, b1, h2b, N2_DST, DH);

    // ---- Layer 2: h2 -> out (fp32 output, BM=64) ----
    gather_mean_bf16_kernel<<<(N3_DST + 3) / 4, 256, 0, stream>>>(h2b, off2, eidx, hn2b, N3_DST);
    gemm_dual<1, 4, false, false><<<dim3(DOUT / 64, (N3_DST + 63) / 64), 256, 0, stream>>>(
        h2b, hn2b, Ws2t, Wn2t, b2, out, N3_DST, DOUT);
}

// Round 6
// 506.025 us; speedup vs baseline: 2.6743x; 1.0059x over previous
//
#include <hip/hip_runtime.h>

// Problem constants (from reference file)
#define N0_SRC 200000
#define N1_DST 50000
#define N2_DST 12000
#define N3_DST 3000
#define NTOT_DST 65000   // N1+N2+N3 (multiple of 4)
#define DH 256           // D_IN == D_H == 256
#define DOUT 64
#define EMAX_TOT 650000  // E0+E1+E2

// conv_trans_zero one-shot block partition (no grid-stride: max TLP, R5 lesson)
#define CONVB 25000   // 51.2M floats / 8 per thread / 256 threads (exact)
#define TRANSB 1536   // 256 blocks x 6 weight matrices
#define ZEROB 254     // ceil(65000/256)

typedef __attribute__((ext_vector_type(8))) short short8;
typedef __attribute__((ext_vector_type(4))) float f32x4;

__device__ __forceinline__ ushort f2bf(float f) {
    union { float f; uint32_t u; } v; v.f = f;
    uint32_t r = (v.u + 0x7FFF + ((v.u >> 16) & 1)) >> 16;  // RNE
    return (ushort)r;
}
__device__ __forceinline__ float bf2f(ushort u) {
    union { uint32_t u; float f; } v; v.u = ((uint32_t)u) << 16;
    return v.f;
}

// global -> LDS direct copy, 16B per lane. LDS dest is wave-uniform base +
// lane*16 (m104); caller passes the wave-uniform LDS base pointer.
__device__ __forceinline__ void gload16(const ushort* g, ushort* l) {
    __builtin_amdgcn_global_load_lds(
        (const __attribute__((address_space(1))) unsigned int*)g,
        (__attribute__((address_space(3))) unsigned int*)l,
        16, 0, 0);
}

// ---------------------------------------------------------------------------
// One-shot partitioned staging kernel (R5 lesson: grid-stride + hist-head ran
// at 1.95 TB/s; one-shot independent threads are the proven-fast form).
// [0,CONVB): convert ALL of x fp32->bf16, 8 floats/thread, exact fit.
// [CONVB,CONVB+TRANSB): six weight transposes W[K][N] -> Wt[N][K] bf16.
// [CONVB+TRANSB,+ZEROB): zero the CSR count array.
// ---------------------------------------------------------------------------
__global__ __launch_bounds__(256) void conv_trans_zero(
    const float* __restrict__ x, ushort* __restrict__ xb,
    const float* __restrict__ W0, const float* __restrict__ W1,
    const float* __restrict__ W2, const float* __restrict__ W3,
    const float* __restrict__ W4, const float* __restrict__ W5,
    ushort* __restrict__ Wt, int* __restrict__ cnt) {
    int bid = blockIdx.x, t = threadIdx.x;
    if (bid < CONVB) {
        long i = ((long)bid * 256 + t) * 8;
        float4 a = *(const float4*)(x + i);
        float4 b = *(const float4*)(x + i + 4);
        ushort4 o0, o1;
        o0.x = f2bf(a.x); o0.y = f2bf(a.y); o0.z = f2bf(a.z); o0.w = f2bf(a.w);
        o1.x = f2bf(b.x); o1.y = f2bf(b.y); o1.z = f2bf(b.z); o1.w = f2bf(b.w);
        *(ushort4*)(xb + i) = o0;
        *(ushort4*)(xb + i + 4) = o1;
        return;
    }
    if (bid < CONVB + TRANSB) {
        int tb = bid - CONVB;
        int wy = tb >> 8;
        int wx = tb & 255;
        const float* W; int Ndim; ushort* o;
        switch (wy) {
            case 0: W = W0; Ndim = 256; o = Wt; break;
            case 1: W = W1; Ndim = 256; o = Wt + 65536; break;
            case 2: W = W2; Ndim = 256; o = Wt + 131072; break;
            case 3: W = W3; Ndim = 256; o = Wt + 196608; break;
            case 4: W = W4; Ndim = 64;  o = Wt + 262144; break;
            default: W = W5; Ndim = 64; o = Wt + 278528; break;
        }
        int id = wx * 256 + t;  // id = n*256 + k
        int n = id >> 8;
        int k = id & 255;
        if (n >= Ndim) return;
        o[id] = f2bf(W[k * Ndim + n]);
        return;
    }
    int z = (bid - CONVB - TRANSB) * 256 + t;
    if (z < NTOT_DST) cnt[z] = 0;
}

// ---------------------------------------------------------------------------
// Batched histogram over all 3 layers (one edge per thread).
// ---------------------------------------------------------------------------
__global__ void hist3_kernel(const int* __restrict__ d0, int E0,
                             const int* __restrict__ d1, int E1,
                             const int* __restrict__ d2, int E2,
                             int* __restrict__ cnt) {
    int layer = blockIdx.y;
    const int* dst; int E; int base;
    if (layer == 0)      { dst = d0; E = E0; base = 0; }
    else if (layer == 1) { dst = d1; E = E1; base = N1_DST; }
    else                 { dst = d2; E = E2; base = N1_DST + N2_DST; }
    int e = blockIdx.x * 256 + threadIdx.x;
    if (e < E) atomicAdd(&cnt[base + dst[e]], 1);
}

// ---------------------------------------------------------------------------
// fill3: scatter edges into CSR slots (cursor atomics).
// ---------------------------------------------------------------------------
__global__ void fill3_kernel(const int* __restrict__ s0, const int* __restrict__ d0, int E0,
                             const int* __restrict__ s1, const int* __restrict__ d1, int E1,
                             const int* __restrict__ s2, const int* __restrict__ d2, int E2,
                             int* __restrict__ cursor, int* __restrict__ eidx) {
    int layer = blockIdx.y;
    const int* src; const int* dst; int E; int base;
    if (layer == 0)      { src = s0; dst = d0; E = E0; base = 0; }
    else if (layer == 1) { src = s1; dst = d1; E = E1; base = N1_DST; }
    else                 { src = s2; dst = d2; E = E2; base = N1_DST + N2_DST; }
    int e = blockIdx.x * 256 + threadIdx.x;
    if (e < E) {
        int p = atomicAdd(&cursor[base + dst[e]], 1);
        eidx[p] = src[e];
    }
}

// ---------------------------------------------------------------------------
// 2-phase coalesced exclusive scan (n multiple of 4; 64 blocks).
// ---------------------------------------------------------------------------
__global__ void scan_phase_a(const int* __restrict__ cnt, int* __restrict__ partial, int n) {
    __shared__ int red[4];
    int t = threadIdx.x;
    int i = blockIdx.x * 1024 + t * 4;
    int s = 0;
    if (i + 3 < n) {
        int4 v = *(const int4*)(cnt + i);
        s = v.x + v.y + v.z + v.w;
    }
#pragma unroll
    for (int d = 32; d; d >>= 1) s += __shfl_down(s, d, 64);
    if ((t & 63) == 0) red[t >> 6] = s;
    __syncthreads();
    if (t == 0) partial[blockIdx.x] = red[0] + red[1] + red[2] + red[3];
}

__global__ void scan_phase_c(const int* __restrict__ cnt, const int* __restrict__ partial,
                             int* __restrict__ off, int* __restrict__ cursor, int n) {
    __shared__ int tsum[256];
    __shared__ int pbase;
    int t = threadIdx.x;
    if (t < 64) {
        int own = partial[t];
        int v = own;
#pragma unroll
        for (int d = 1; d < 64; d <<= 1) {
            int u = __shfl_up(v, d, 64);
            if (t >= d) v += u;
        }
        if (t == (int)blockIdx.x) pbase = v - own;  // exclusive prefix
    }
    int i = blockIdx.x * 1024 + t * 4;
    int4 c = make_int4(0, 0, 0, 0);
    if (i + 3 < n) c = *(const int4*)(cnt + i);
    int s = c.x + c.y + c.z + c.w;
    tsum[t] = s;
    __syncthreads();
#pragma unroll
    for (int d = 1; d < 256; d <<= 1) {
        int u = (t >= d) ? tsum[t - d] : 0;
        __syncthreads();
        tsum[t] += u;
        __syncthreads();
    }
    int base = pbase + tsum[t] - s;
    if (i + 3 < n) {
        int4 ov;
        ov.x = base;
        ov.y = ov.x + c.x;
        ov.z = ov.y + c.y;
        ov.w = ov.z + c.z;
        *(int4*)(off + i) = ov;
        *(int4*)(cursor + i) = ov;
        if (i + 4 == n) off[n] = ov.w + c.w;
    }
}

// ---------------------------------------------------------------------------
// Gather-mean bf16 in -> bf16 out. One wave per dst; lane owns 4 feats.
// 8-wide masked batches: 8 outstanding 8B loads per round for MLP.
// ---------------------------------------------------------------------------
__global__ void gather_mean_bf16_kernel(const ushort* __restrict__ h,
                                        const int* __restrict__ off,
                                        const int* __restrict__ eidx,
                                        ushort* __restrict__ hn,
                                        int num_dst) {
    int w = blockIdx.x * 4 + (threadIdx.x >> 6);
    int lane = threadIdx.x & 63;
    if (w >= num_dst) return;
    int beg = off[w];
    int end = off[w + 1];
    float a0 = 0.f, a1 = 0.f, a2 = 0.f, a3 = 0.f;
    for (int i = beg; i < end; i += 8) {
        int rem = end - i;  // >= 1
        int j1 = i + (rem > 1 ? 1 : 0);
        int j2 = i + (rem > 2 ? 2 : 0);
        int j3 = i + (rem > 3 ? 3 : 0);
        int j4 = i + (rem > 4 ? 4 : 0);
        int j5 = i + (rem > 5 ? 5 : 0);
        int j6 = i + (rem > 6 ? 6 : 0);
        int j7 = i + (rem > 7 ? 7 : 0);
        float m1 = rem > 1 ? 1.f : 0.f;
        float m2 = rem > 2 ? 1.f : 0.f;
        float m3 = rem > 3 ? 1.f : 0.f;
        float m4 = rem > 4 ? 1.f : 0.f;
        float m5 = rem > 5 ? 1.f : 0.f;
        float m6 = rem > 6 ? 1.f : 0.f;
        float m7 = rem > 7 ? 1.f : 0.f;
        int s0 = eidx[i],  s1 = eidx[j1], s2 = eidx[j2], s3 = eidx[j3];
        int s4 = eidx[j4], s5 = eidx[j5], s6 = eidx[j6], s7 = eidx[j7];
        ushort4 v0 = ((const ushort4*)(h + (size_t)s0 * DH))[lane];
        ushort4 v1 = ((const ushort4*)(h + (size_t)s1 * DH))[lane];
        ushort4 v2 = ((const ushort4*)(h + (size_t)s2 * DH))[lane];
        ushort4 v3 = ((const ushort4*)(h + (size_t)s3 * DH))[lane];
        ushort4 v4 = ((const ushort4*)(h + (size_t)s4 * DH))[lane];
        ushort4 v5 = ((const ushort4*)(h + (size_t)s5 * DH))[lane];
        ushort4 v6 = ((const ushort4*)(h + (size_t)s6 * DH))[lane];
        ushort4 v7 = ((const ushort4*)(h + (size_t)s7 * DH))[lane];
        a0 += (bf2f(v0.x) + m1 * bf2f(v1.x) + m2 * bf2f(v2.x) + m3 * bf2f(v3.x)) +
              (m4 * bf2f(v4.x) + m5 * bf2f(v5.x) + m6 * bf2f(v6.x) + m7 * bf2f(v7.x));
        a1 += (bf2f(v0.y) + m1 * bf2f(v1.y) + m2 * bf2f(v2.y) + m3 * bf2f(v3.y)) +
              (m4 * bf2f(v4.y) + m5 * bf2f(v5.y) + m6 * bf2f(v6.y) + m7 * bf2f(v7.y));
        a2 += (bf2f(v0.z) + m1 * bf2f(v1.z) + m2 * bf2f(v2.z) + m3 * bf2f(v3.z)) +
              (m4 * bf2f(v4.z) + m5 * bf2f(v5.z) + m6 * bf2f(v6.z) + m7 * bf2f(v7.z));
        a3 += (bf2f(v0.w) + m1 * bf2f(v1.w) + m2 * bf2f(v2.w) + m3 * bf2f(v3.w)) +
              (m4 * bf2f(v4.w) + m5 * bf2f(v5.w) + m6 * bf2f(v6.w) + m7 * bf2f(v7.w));
    }
    float inv = 1.0f / fmaxf((float)(end - beg), 1.0f);
    ushort4 o;
    o.x = f2bf(a0 * inv); o.y = f2bf(a1 * inv);
    o.z = f2bf(a2 * inv); o.w = f2bf(a3 * inv);
    *(ushort4*)(hn + (size_t)w * DH + lane * 4) = o;
}

// ---------------------------------------------------------------------------
// Merged-dual MFMA GEMM: C[M,N] = Ad@Ws + An@Wn + bias (K=256), both passes
// in ONE k-loop. Staging via global_load_lds width-16 into LINEAR LDS tiles
// [rows][32] (64B rows). Bank conflicts handled by the both-sides XOR swizzle
// (rule 21). BM = MT*64, BN = NT*16. M-tail: staged row clamped to M-1.
// ---------------------------------------------------------------------------
template <int MT, int NT, bool RELU, bool OUT_BF16>
__global__ __launch_bounds__(256) void gemm_dual(const ushort* __restrict__ Ad,
                                                 const ushort* __restrict__ An,
                                                 const ushort* __restrict__ Wst,
                                                 const ushort* __restrict__ Wnt,
                                                 const float* __restrict__ bias,
                                                 void* __restrict__ Cv,
                                                 int M, int N) {
    const int K = 256;
    const int BM = MT * 64;
    const int BN = NT * 16;
    __shared__ __align__(16) ushort lds[(2 * BM + 2 * BN) * 32];
    ushort* Asd = lds;
    ushort* Asn = lds + BM * 32;
    ushort* Bss = lds + 2 * BM * 32;
    ushort* Bsn = lds + 2 * BM * 32 + BN * 32;

    int tid  = threadIdx.x;
    int lane = tid & 63;
    int wid  = tid >> 6;
    int q    = lane >> 4;
    int mr   = lane & 15;
    int row0 = blockIdx.y * BM;
    int col0 = blockIdx.x * BN;

    f32x4 acc[MT][NT];
#pragma unroll
    for (int i = 0; i < MT; ++i)
#pragma unroll
        for (int j = 0; j < NT; ++j) acc[i][j] = (f32x4){0.f, 0.f, 0.f, 0.f};

    for (int k0 = 0; k0 < K; k0 += 32) {
        // Stage A tiles (BM x 32, clamped rows), both matrices.
#pragma unroll
        for (int c = 0; c < MT; ++c) {
            int chunk = c * 256 + tid;               // 16B chunk index in tile
            int r   = chunk >> 2;                    // tile row
            int sg  = (chunk & 3) ^ ((r >> 1) & 3);  // swizzled global segment
            int row = row0 + r;
            if (row > M - 1) row = M - 1;
            const ushort* gd = Ad + (size_t)row * K + k0 + sg * 8;
            const ushort* gn = An + (size_t)row * K + k0 + sg * 8;
            int cb = (c * 256 + (tid & ~63)) * 8;    // wave-uniform LDS base
            gload16(gd, Asd + cb);
            gload16(gn, Asn + cb);
        }
        // Stage B tiles (BN x 32), both weight matrices. Rows always valid.
#pragma unroll
        for (int c = 0; c < NT / 4; ++c) {
            int chunk = c * 256 + tid;
            int r  = chunk >> 2;
            int sg = (chunk & 3) ^ ((r >> 1) & 3);
            const ushort* gs = Wst + (size_t)(col0 + r) * K + k0 + sg * 8;
            const ushort* gw = Wnt + (size_t)(col0 + r) * K + k0 + sg * 8;
            int cb = (c * 256 + (tid & ~63)) * 8;
            gload16(gs, Bss + cb);
            gload16(gw, Bsn + cb);
        }
        __syncthreads();  // compiler drains vmcnt(0) before s_barrier

        short8 ad[MT], an[MT];
#pragma unroll
        for (int mt = 0; mt < MT; ++mt) {
            int rho = wid * (MT * 16) + mt * 16 + mr;
            int o   = rho * 32 + ((q ^ ((rho >> 1) & 3)) * 8);
            ad[mt] = *(const short8*)(Asd + o);
            an[mt] = *(const short8*)(Asn + o);
        }
#pragma unroll
        for (int nt = 0; nt < NT; ++nt) {
            int rho = nt * 16 + mr;
            int o   = rho * 32 + ((q ^ ((rho >> 1) & 3)) * 8);
            short8 bs = *(const short8*)(Bss + o);
            short8 bn = *(const short8*)(Bsn + o);
#pragma unroll
            for (int mt = 0; mt < MT; ++mt)
                acc[mt][nt] = __builtin_amdgcn_mfma_f32_16x16x32_bf16(
                    ad[mt], bs, acc[mt][nt], 0, 0, 0);
#pragma unroll
            for (int mt = 0; mt < MT; ++mt)
                acc[mt][nt] = __builtin_amdgcn_mfma_f32_16x16x32_bf16(
                    an[mt], bn, acc[mt][nt], 0, 0, 0);
        }
        __syncthreads();
    }

    // Epilogue: C/D layout col = lane&15, row = quad*4 + reg
#pragma unroll
    for (int mt = 0; mt < MT; ++mt) {
#pragma unroll
        for (int i = 0; i < 4; ++i) {
            int row = row0 + wid * (MT * 16) + mt * 16 + q * 4 + i;
            if (row >= M) continue;
#pragma unroll
            for (int nt = 0; nt < NT; ++nt) {
                int col = col0 + nt * 16 + mr;
                float v = acc[mt][nt][i] + bias[col];
                if (RELU) v = fmaxf(v, 0.0f);
                if (OUT_BF16) ((ushort*)Cv)[(size_t)row * N + col] = f2bf(v);
                else          ((float*)Cv)[(size_t)row * N + col] = v;
            }
        }
    }
}

extern "C" void kernel_launch(void* const* d_in, const int* in_sizes, int n_in,
                              void* d_out, int out_size, void* d_ws, size_t ws_size,
                              hipStream_t stream) {
    const float* x    = (const float*)d_in[0];
    const int* src0   = (const int*)d_in[1];
    const int* dst0   = (const int*)d_in[2];
    const int* src1   = (const int*)d_in[3];
    const int* dst1   = (const int*)d_in[4];
    const int* src2   = (const int*)d_in[5];
    const int* dst2   = (const int*)d_in[6];
    const float* Ws0  = (const float*)d_in[10];
    const float* Wn0  = (const float*)d_in[11];
    const float* b0   = (const float*)d_in[12];
    const float* Ws1  = (const float*)d_in[13];
    const float* Wn1  = (const float*)d_in[14];
    const float* b1   = (const float*)d_in[15];
    const float* Ws2  = (const float*)d_in[16];
    const float* Wn2  = (const float*)d_in[17];
    const float* b2   = (const float*)d_in[18];
    float* out = (float*)d_out;

    int E0 = in_sizes[1];
    int E1 = in_sizes[3];
    int E2 = in_sizes[5];

    // Workspace layout (shorts first, then ints; all 16B aligned)
    ushort* wsu  = (ushort*)d_ws;
    ushort* xb   = wsu;                               // N0*256 (all of x, bf16)
    ushort* hn0b = xb   + (size_t)N0_SRC * DH;        // N1*256
    ushort* h1b  = hn0b + (size_t)N1_DST * DH;        // N1*256
    ushort* hn1b = h1b  + (size_t)N1_DST * DH;        // N2*256
    ushort* h2b  = hn1b + (size_t)N2_DST * DH;        // N2*256
    ushort* hn2b = h2b  + (size_t)N2_DST * DH;        // N3*256
    ushort* Wt   = hn2b + (size_t)N3_DST * DH;        // 294912 shorts (6 weights)
    ushort* Ws0t = Wt;
    ushort* Wn0t = Wt + 65536;
    ushort* Ws1t = Wt + 131072;
    ushort* Wn1t = Wt + 196608;
    ushort* Ws2t = Wt + 262144;
    ushort* Wn2t = Wt + 278528;
    int* cnt     = (int*)(Wt + 294912);               // NTOT_DST
    int* off     = cnt + NTOT_DST;                    // NTOT_DST+1 (+pad)
    int* cursor  = off + NTOT_DST + 4;                // NTOT_DST
    int* eidx    = cursor + NTOT_DST;                 // EMAX_TOT
    int* partial = eidx + EMAX_TOT;                   // 64 block partials

    int Emax = max(max(E0, E1), E2);
    int nb = (NTOT_DST + 1023) / 1024;  // = 64

    // 1) one-shot convert + weight transposes + cnt zero
    conv_trans_zero<<<CONVB + TRANSB + ZEROB, 256, 0, stream>>>(
        x, xb, Ws0, Wn0, Ws1, Wn1, Ws2, Wn2, Wt, cnt);
    // 2) histogram
    hist3_kernel<<<dim3((Emax + 255) / 256, 3), 256, 0, stream>>>(
        dst0, E0, dst1, E1, dst2, E2, cnt);
    // 3-4) scan
    scan_phase_a<<<nb, 256, 0, stream>>>(cnt, partial, NTOT_DST);
    scan_phase_c<<<nb, 256, 0, stream>>>(cnt, partial, off, cursor, NTOT_DST);
    // 5) fill CSR
    fill3_kernel<<<dim3((Emax + 255) / 256, 3), 256, 0, stream>>>(
        src0, dst0, E0, src1, dst1, E1, src2, dst2, E2, cursor, eidx);

    const int* off0 = off;
    const int* off1 = off + N1_DST;
    const int* off2 = off + N1_DST + N2_DST;

    // ---- Layer 0: x -> h1 (gather reads warm bf16 xb) ----
    gather_mean_bf16_kernel<<<(N1_DST + 3) / 4, 256, 0, stream>>>(xb, off0, eidx, hn0b, N1_DST);
    gemm_dual<2, 8, false, true><<<dim3(DH / 128, (N1_DST + 127) / 128), 256, 0, stream>>>(
        xb, hn0b, Ws0t, Wn0t, b0, h1b, N1_DST, DH);

    // ---- Layer 1: h1 -> h2 (ReLU on output) ----
    gather_mean_bf16_kernel<<<(N2_DST + 3) / 4, 256, 0, stream>>>(h1b, off1, eidx, hn1b, N2_DST);
    gemm_dual<2, 8, true, true><<<dim3(DH / 128, (N2_DST + 127) / 128), 256, 0, stream>>>(
        h1b, hn1b, Ws1t, Wn1t, b1, h2b, N2_DST, DH);

    // ---- Layer 2: h2 -> out (fp32 output, BM=64) ----
    gather_mean_bf16_kernel<<<(N3_DST + 3) / 4, 256, 0, stream>>>(h2b, off2, eidx, hn2b, N3_DST);
    gemm_dual<1, 4, false, false><<<dim3(DOUT / 64, (N3_DST + 63) / 64), 256, 0, stream>>>(
        h2b, hn2b, Ws2t, Wn2t, b2, out, N3_DST, DOUT);
}